// Round 11
// baseline (299.095 us; speedup 1.0000x reference)
//
#include <hip/hip_runtime.h>
#include <math.h>

#define N_TOKENS 32768
#define D_MODEL  1024
#define N_EXPERT 16
#define TPB      256
#define NBLK     1024              // 4 blocks/CU, all resident
#define TOKS     32                // tokens per block
#define TPW      8                 // tokens per wave (barrier-free)

typedef float f32x4 __attribute__((ext_vector_type(4)));
typedef float f32x2 __attribute__((ext_vector_type(2)));

#define LO(v) __builtin_shufflevector(v, v, 0, 1)
#define HI(v) __builtin_shufflevector(v, v, 2, 3)

// DPP cross-lane XOR within 16-lane rows (VALU pipe):
//   ^1: quad_perm [1,0,3,2]=0xB1; ^2: quad_perm [2,3,0,1]=0x4E;
//   ^8: row_ror:8 = 0x128 ((i+8) mod 16 == i^8).  (HW-verified rounds 6-10.)
template<int CTRL>
static __device__ __forceinline__ float dpp_xor(float v) {
    return __int_as_float(__builtin_amdgcn_update_dpp(
        0, __float_as_int(v), CTRL, 0xF, 0xF, true));
}

// 16-dim dot via packed fp32: 1 pk_mul + 7 pk_fma + horizontal add.
static __device__ __forceinline__ float dot16(f32x4 x0, f32x4 x1, f32x4 x2, f32x4 x3,
                                              const f32x4* wj) {
    f32x2 a;
    asm("v_pk_mul_f32 %0, %1, %2" : "=v"(a) : "v"(LO(x0)), "v"(LO(wj[0])));
    asm("v_pk_fma_f32 %0, %1, %2, %3" : "=v"(a) : "v"(HI(x0)), "v"(HI(wj[0])), "v"(a));
    asm("v_pk_fma_f32 %0, %1, %2, %3" : "=v"(a) : "v"(LO(x1)), "v"(LO(wj[1])), "v"(a));
    asm("v_pk_fma_f32 %0, %1, %2, %3" : "=v"(a) : "v"(HI(x1)), "v"(HI(wj[1])), "v"(a));
    asm("v_pk_fma_f32 %0, %1, %2, %3" : "=v"(a) : "v"(LO(x2)), "v"(LO(wj[2])), "v"(a));
    asm("v_pk_fma_f32 %0, %1, %2, %3" : "=v"(a) : "v"(HI(x2)), "v"(HI(wj[2])), "v"(a));
    asm("v_pk_fma_f32 %0, %1, %2, %3" : "=v"(a) : "v"(LO(x3)), "v"(LO(wj[3])), "v"(a));
    asm("v_pk_fma_f32 %0, %1, %2, %3" : "=v"(a) : "v"(HI(x3)), "v"(HI(wj[3])), "v"(a));
    return a.x + a.y;
}

// d_out layout (float32, concatenated outputs):
//   [0, 65536)       top_k_indices as floats, row-major [N,2]
//   [65536, 131072)  top_k_scores,            row-major [N,2]
//   [131072]         loss scalar
// d_ws: NBLK slots of 32 floats; slot b: [0..15] expert counts, [16..31] prob sums.

__global__ __launch_bounds__(TPB)
__attribute__((amdgpu_waves_per_eu(4, 4)))
void gate_kernel(const float* __restrict__ inp,
                 const float* __restrict__ W,
                 float* __restrict__ out,
                 float* __restrict__ ws)
{
    const int tid  = threadIdx.x;
    const int wave = tid >> 6;
    const int lane = tid & 63;
    const int p    = lane & 15;               // expert rotation for this lane
    const int wtok0 = blockIdx.x * TOKS + wave * TPW;  // this wave's 8 tokens

    // Lane l owns dims {c*256 + l*4 .. +3, c=0..3}; the 16-lane group q=l>>4
    // covers dims {c*256 + 64q .. +63}; masks 16/32 fold the 4 groups -> full
    // 1024-dim dot per wave.  wreg[j][c] = W[(j^p)][c*256 + l*4] (64 VGPRs,
    // one-time gather, L2-resident).
    f32x4 wreg[N_EXPERT][4];
    #pragma unroll
    for (int j = 0; j < N_EXPERT; ++j)
        #pragma unroll
        for (int c = 0; c < 4; ++c)
            wreg[j][c] = *reinterpret_cast<const f32x4*>(
                W + (j ^ p) * D_MODEL + c * 256 + lane * 4);

    __shared__ float lds_red[4][2][N_EXPERT];  // only the final cnt/ps reduce

    float cnt_acc = 0.f;
    float ps_acc  = 0.f;

    const float* xptr = inp + (size_t)wtok0 * D_MODEL + lane * 4;

#define LOADT(Ra, Rb, Rc, Rd, t) \
    Ra = *reinterpret_cast<const f32x4*>(xptr + (size_t)(t) * D_MODEL);       \
    Rb = *reinterpret_cast<const f32x4*>(xptr + (size_t)(t) * D_MODEL + 256); \
    Rc = *reinterpret_cast<const f32x4*>(xptr + (size_t)(t) * D_MODEL + 512); \
    Rd = *reinterpret_cast<const f32x4*>(xptr + (size_t)(t) * D_MODEL + 768);

    // Full per-token pipeline, all in one wave, no LDS, no barriers:
    // 144-instr dot block -> select-free butterfly (masks 8,4,2,1,16,32) ->
    // top-2 merge butterfly ((val desc, idx asc) == jax.lax.top_k) -> softmax.
#define TOKFULL(Xa, Xb, Xc, Xd, t) do { \
    float a0 =dot16(Xa,Xb,Xc,Xd, wreg[0]),  a1 =dot16(Xa,Xb,Xc,Xd, wreg[1]);  \
    float a2 =dot16(Xa,Xb,Xc,Xd, wreg[2]),  a3 =dot16(Xa,Xb,Xc,Xd, wreg[3]);  \
    float a4 =dot16(Xa,Xb,Xc,Xd, wreg[4]),  a5 =dot16(Xa,Xb,Xc,Xd, wreg[5]);  \
    float a6 =dot16(Xa,Xb,Xc,Xd, wreg[6]),  a7 =dot16(Xa,Xb,Xc,Xd, wreg[7]);  \
    float a8 =dot16(Xa,Xb,Xc,Xd, wreg[8]),  a9 =dot16(Xa,Xb,Xc,Xd, wreg[9]);  \
    float a10=dot16(Xa,Xb,Xc,Xd, wreg[10]), a11=dot16(Xa,Xb,Xc,Xd, wreg[11]); \
    float a12=dot16(Xa,Xb,Xc,Xd, wreg[12]), a13=dot16(Xa,Xb,Xc,Xd, wreg[13]); \
    float a14=dot16(Xa,Xb,Xc,Xd, wreg[14]), a15=dot16(Xa,Xb,Xc,Xd, wreg[15]); \
    float b0 = a0 + dpp_xor<0x128>(a8);  \
    float b1 = a1 + dpp_xor<0x128>(a9);  \
    float b2 = a2 + dpp_xor<0x128>(a10); \
    float b3 = a3 + dpp_xor<0x128>(a11); \
    float b4 = a4 + dpp_xor<0x128>(a12); \
    float b5 = a5 + dpp_xor<0x128>(a13); \
    float b6 = a6 + dpp_xor<0x128>(a14); \
    float b7 = a7 + dpp_xor<0x128>(a15); \
    float c0 = b0 + __shfl_xor(b4, 4); \
    float c1 = b1 + __shfl_xor(b5, 4); \
    float c2 = b2 + __shfl_xor(b6, 4); \
    float c3 = b3 + __shfl_xor(b7, 4); \
    float d0_ = c0 + dpp_xor<0x4E>(c2); \
    float d1_ = c1 + dpp_xor<0x4E>(c3); \
    float s0  = d0_ + dpp_xor<0xB1>(d1_); \
    s0 += __shfl_xor(s0, 16); \
    s0 += __shfl_xor(s0, 32); \
    float v1 = s0;  int i1 = p; \
    float v2 = -INFINITY;  int i2 = 0; \
    _Pragma("unroll") \
    for (int m = 1; m <= 8; m <<= 1) { \
        float o1 = __shfl_xor(v1, m); \
        int  oi1 = __shfl_xor(i1, m); \
        float o2 = __shfl_xor(v2, m); \
        int  oi2 = __shfl_xor(i2, m); \
        bool afirst = (v1 > o1) || (v1 == o1 && i1 < oi1); \
        float c1v = afirst ? v1 : o1;   int c1i = afirst ? i1 : oi1; \
        float bv  = afirst ? o1 : v1;   int bi  = afirst ? oi1 : i1; \
        float sv  = afirst ? v2 : o2;   int si  = afirst ? i2 : oi2; \
        bool sgt  = (bv > sv) || (bv == sv && bi < si); \
        v1 = c1v; i1 = c1i; \
        v2 = sgt ? bv : sv;  i2 = sgt ? bi : si; \
    } \
    float tt = expf(v2 - v1); \
    float p1 = 1.f / (1.f + tt); \
    float p2 = tt * p1; \
    const int tok = wtok0 + (t); \
    if (lane == 0) { \
        *reinterpret_cast<float2*>(out + 2 * tok) = \
            make_float2((float)i1, (float)i2); \
        *reinterpret_cast<float2*>(out + 2 * N_TOKENS + 2 * tok) = \
            make_float2(p1, p2); \
    } \
    if (lane < N_EXPERT) { \
        cnt_acc += (p == i1 ? 1.f : 0.f) + (p == i2 ? 1.f : 0.f); \
        ps_acc  += (p == i1 ? p1  : 0.f) + (p == i2 ? p2  : 0.f); \
    } \
} while (0)

    // 2-token A/B ring, fully static, no cross-wave coupling anywhere.
    f32x4 xA0, xA1, xA2, xA3, xB0, xB1, xB2, xB3;
    LOADT(xA0, xA1, xA2, xA3, 0)
    LOADT(xB0, xB1, xB2, xB3, 1)
    TOKFULL(xA0, xA1, xA2, xA3, 0); LOADT(xA0, xA1, xA2, xA3, 2)
    TOKFULL(xB0, xB1, xB2, xB3, 1); LOADT(xB0, xB1, xB2, xB3, 3)
    TOKFULL(xA0, xA1, xA2, xA3, 2); LOADT(xA0, xA1, xA2, xA3, 4)
    TOKFULL(xB0, xB1, xB2, xB3, 3); LOADT(xB0, xB1, xB2, xB3, 5)
    TOKFULL(xA0, xA1, xA2, xA3, 4); LOADT(xA0, xA1, xA2, xA3, 6)
    TOKFULL(xB0, xB1, xB2, xB3, 5); LOADT(xB0, xB1, xB2, xB3, 7)
    TOKFULL(xA0, xA1, xA2, xA3, 6);
    TOKFULL(xB0, xB1, xB2, xB3, 7);

    // Final cnt/ps reduction (single barrier in the whole kernel).
    if (lane < N_EXPERT) {
        lds_red[wave][0][lane] = cnt_acc;
        lds_red[wave][1][lane] = ps_acc;
    }
    __syncthreads();
    if (tid < 32) {
        const int el = tid & 15;
        const int which = tid >> 4;   // 0 = cnt, 1 = ps
        float v = lds_red[0][which][el] + lds_red[1][which][el]
                + lds_red[2][which][el] + lds_red[3][which][el];
        ws[blockIdx.x * 32 + tid] = v;
    }
#undef LOADT
#undef TOKFULL
}

__global__ __launch_bounds__(1024)
void loss_kernel(const float* __restrict__ ws, float* __restrict__ out)
{
    // Reduce NBLK x 32 partial slots with 1024 threads (coalesced 256B/wave),
    // then dot counts x prob-sums.
    __shared__ float red[32][33];   // +1 pad
    __shared__ float col[32];
    const int tid = threadIdx.x;    // 0..1023
    const int c   = tid & 31;       // column within slot
    const int r   = tid >> 5;       // 0..31 slot-chunk
    float s0 = 0.f, s1 = 0.f, s2 = 0.f, s3 = 0.f;
    #pragma unroll
    for (int k = 0; k < 32; k += 4) {
        s0 += ws[(size_t)(r + (k + 0) * 32) * 32 + c];
        s1 += ws[(size_t)(r + (k + 1) * 32) * 32 + c];
        s2 += ws[(size_t)(r + (k + 2) * 32) * 32 + c];
        s3 += ws[(size_t)(r + (k + 3) * 32) * 32 + c];
    }
    red[r][c] = (s0 + s1) + (s2 + s3);
    __syncthreads();
    if (tid < 32) {
        float t = 0.f;
        #pragma unroll
        for (int k = 0; k < 32; ++k) t += red[k][tid];
        col[tid] = t;
    }
    __syncthreads();
    if (tid == 0) {
        float sum = 0.f;
        #pragma unroll
        for (int e = 0; e < N_EXPERT; ++e)
            sum += col[e] * col[16 + e];
        out[4 * N_TOKENS] = sum * (float)N_EXPERT
                          / ((float)N_TOKENS * (float)N_TOKENS);
    }
}

extern "C" void kernel_launch(void* const* d_in, const int* in_sizes, int n_in,
                              void* d_out, int out_size, void* d_ws, size_t ws_size,
                              hipStream_t stream)
{
    const float* inp = (const float*)d_in[0];
    const float* W   = (const float*)d_in[1];
    float* out = (float*)d_out;
    float* ws  = (float*)d_ws;

    gate_kernel<<<NBLK, TPB, 0, stream>>>(inp, W, out, ws);
    loss_kernel<<<1, 1024, 0, stream>>>(ws, out);
}

// Round 12
// 39.205 us; speedup vs baseline: 7.6290x; 7.6290x over previous
//
#include <hip/hip_runtime.h>
#include <math.h>

#define N_TOKENS 32768
#define D_MODEL  1024
#define N_EXPERT 16
#define TPB      256
#define NBLK     1024              // 4 blocks/CU
#define TOKS     32                // tokens per block (2 batches of 16)
#define BATCH    16
#define EP       (N_EXPERT + 1)    // padded inner dim

typedef float f32x4 __attribute__((ext_vector_type(4)));
typedef float f32x2 __attribute__((ext_vector_type(2)));

// DPP cross-lane XOR within 16-lane rows (VALU pipe):
//   ^1: quad_perm [1,0,3,2]=0xB1; ^2: quad_perm [2,3,0,1]=0x4E;
//   ^8: row_ror:8 = 0x128 ((i+8) mod 16 == i^8).  (HW-verified rounds 6-11.)
template<int CTRL>
static __device__ __forceinline__ float dpp_xor(float v) {
    return __int_as_float(__builtin_amdgcn_update_dpp(
        0, __float_as_int(v), CTRL, 0xF, 0xF, true));
}

// Packed fp32 dot over 4 dims: v_pk_mul + v_pk_fma + horizontal add.
// NOTE: w must be passed BY VALUE (never a pointer into wreg[] — r11 lesson:
// pointer-indexing a private array sends it to scratch, 211MB spill traffic).
static __device__ __forceinline__ float dot4pk(f32x4 x, f32x4 w) {
    f32x2 xl = __builtin_shufflevector(x, x, 0, 1);
    f32x2 xh = __builtin_shufflevector(x, x, 2, 3);
    f32x2 wl = __builtin_shufflevector(w, w, 0, 1);
    f32x2 wh = __builtin_shufflevector(w, w, 2, 3);
    f32x2 m, r;
    asm("v_pk_mul_f32 %0, %1, %2" : "=v"(m) : "v"(xl), "v"(wl));
    asm("v_pk_fma_f32 %0, %1, %2, %3" : "=v"(r) : "v"(xh), "v"(wh), "v"(m));
    return r.x + r.y;
}

// d_out layout (float32, concatenated outputs):
//   [0, 65536)       top_k_indices as floats, row-major [N,2]
//   [65536, 131072)  top_k_scores,            row-major [N,2]
//   [131072]         loss scalar
// d_ws: NBLK slots of 32 floats; slot b: [0..15] expert counts, [16..31] prob sums.

__global__ __launch_bounds__(TPB)
__attribute__((amdgpu_waves_per_eu(4, 4)))
void gate_kernel(const float* __restrict__ inp,
                 const float* __restrict__ W,
                 float* __restrict__ out,
                 float* __restrict__ ws)
{
    const int tid  = threadIdx.x;
    const int wave = tid >> 6;
    const int lane = tid & 63;
    const int p    = lane & 15;               // expert rotation for this lane
    const int d0   = wave * 256 + lane * 4;   // this lane's 4 dims
    const int base = blockIdx.x * TOKS;

    // XOR-rotated W fragment: wreg[j] = W[j^p][d0..d0+3].  64 VGPRs.
    f32x4 wreg[N_EXPERT];
    #pragma unroll
    for (int j = 0; j < N_EXPERT; ++j)
        wreg[j] = *reinterpret_cast<const f32x4*>(W + (j ^ p) * D_MODEL + d0);

    __shared__ float lds_part[2][BATCH][4][EP];   // double-buffered
    __shared__ float lds_red[4][2][N_EXPERT];     // final cnt/ps reduce

    float cnt_acc = 0.f;
    float ps_acc  = 0.f;

    const float* xptr = inp + (size_t)base * D_MODEL + d0;

// runtime t is fine here: it only feeds the address ALU, not a register index
#define LOADX(xr, t) xr = *reinterpret_cast<const f32x4*>(xptr + (size_t)(t) * D_MODEL);

    // Select-free transpose-reduce: stage m does b[j] = a[j] + xor_m(a[j^m]).
    // Masks 8,2,1 via DPP; masks 4,16,32 via shfl.  slot may be runtime (LDS
    // addressing is register-based).
#define DOTOK(xv, slot, BUF) do { \
    float a0 =dot4pk(xv,wreg[0]),  a1 =dot4pk(xv,wreg[1]);  \
    float a2 =dot4pk(xv,wreg[2]),  a3 =dot4pk(xv,wreg[3]);  \
    float a4 =dot4pk(xv,wreg[4]),  a5 =dot4pk(xv,wreg[5]);  \
    float a6 =dot4pk(xv,wreg[6]),  a7 =dot4pk(xv,wreg[7]);  \
    float a8 =dot4pk(xv,wreg[8]),  a9 =dot4pk(xv,wreg[9]);  \
    float a10=dot4pk(xv,wreg[10]), a11=dot4pk(xv,wreg[11]); \
    float a12=dot4pk(xv,wreg[12]), a13=dot4pk(xv,wreg[13]); \
    float a14=dot4pk(xv,wreg[14]), a15=dot4pk(xv,wreg[15]); \
    float b0 = a0 + dpp_xor<0x128>(a8);  \
    float b1 = a1 + dpp_xor<0x128>(a9);  \
    float b2 = a2 + dpp_xor<0x128>(a10); \
    float b3 = a3 + dpp_xor<0x128>(a11); \
    float b4 = a4 + dpp_xor<0x128>(a12); \
    float b5 = a5 + dpp_xor<0x128>(a13); \
    float b6 = a6 + dpp_xor<0x128>(a14); \
    float b7 = a7 + dpp_xor<0x128>(a15); \
    float c0 = b0 + __shfl_xor(b4, 4); \
    float c1 = b1 + __shfl_xor(b5, 4); \
    float c2 = b2 + __shfl_xor(b6, 4); \
    float c3 = b3 + __shfl_xor(b7, 4); \
    float d0_ = c0 + dpp_xor<0x4E>(c2); \
    float d1_ = c1 + dpp_xor<0x4E>(c3); \
    float s0  = d0_ + dpp_xor<0xB1>(d1_); \
    s0 += __shfl_xor(s0, 16); \
    s0 += __shfl_xor(s0, 32); \
    if (lane < N_EXPERT) BUF[slot][wave][lane] = s0; \
} while (0)

    // Phase B: 16 tokens x 16 expert-lanes: sum 4 wave partials, top-2
    // merge butterfly ((val desc, idx asc) == jax.lax.top_k), 2-way softmax.
#define PHASEB(BUF, TOKBASE) do { \
    const int tgrp = tid >> 4; \
    const int el   = tid & 15; \
    float v1 = BUF[tgrp][0][el] + BUF[tgrp][1][el] \
             + BUF[tgrp][2][el] + BUF[tgrp][3][el]; \
    int   i1 = el; \
    float v2 = -INFINITY; \
    int   i2 = 0; \
    _Pragma("unroll") \
    for (int m = 1; m <= 8; m <<= 1) { \
        float o1 = __shfl_xor(v1, m); \
        int  oi1 = __shfl_xor(i1, m); \
        float o2 = __shfl_xor(v2, m); \
        int  oi2 = __shfl_xor(i2, m); \
        bool afirst = (v1 > o1) || (v1 == o1 && i1 < oi1); \
        float c1v = afirst ? v1 : o1;   int c1i = afirst ? i1 : oi1; \
        float bv  = afirst ? o1 : v1;   int bi  = afirst ? oi1 : i1; \
        float sv  = afirst ? v2 : o2;   int si  = afirst ? i2 : oi2; \
        bool sgt  = (bv > sv) || (bv == sv && bi < si); \
        v1 = c1v; i1 = c1i; \
        v2 = sgt ? bv : sv;  i2 = sgt ? bi : si; \
    } \
    float tt = expf(v2 - v1); \
    float p1 = 1.f / (1.f + tt); \
    float p2 = tt * p1; \
    const int tok = (TOKBASE) + tgrp; \
    if (el == 0) { \
        *reinterpret_cast<float2*>(out + 2 * tok) = \
            make_float2((float)i1, (float)i2); \
        *reinterpret_cast<float2*>(out + 2 * N_TOKENS + 2 * tok) = \
            make_float2(p1, p2); \
    } \
    cnt_acc += (el == i1 ? 1.f : 0.f) + (el == i2 ? 1.f : 0.f); \
    ps_acc  += (el == i1 ? p1  : 0.f) + (el == i2 ? p2  : 0.f); \
} while (0)

    f32x4 x0, x1, x2, x3;

    // ---- Batch 0: tokens 0..15.  ROLLED loop (code-size experiment): body
    // is ~370 instrs (~3KB) instead of a 24KB straight-line unroll. ----
    LOADX(x0, 0) LOADX(x1, 1) LOADX(x2, 2) LOADX(x3, 3)
    #pragma clang loop unroll(disable)
    for (int it = 0; it < 3; ++it) {
        const int t = it * 4;
        DOTOK(x0, t + 0, lds_part[0]); LOADX(x0, t + 4)
        DOTOK(x1, t + 1, lds_part[0]); LOADX(x1, t + 5)
        DOTOK(x2, t + 2, lds_part[0]); LOADX(x2, t + 6)
        DOTOK(x3, t + 3, lds_part[0]); LOADX(x3, t + 7)
    }
    // tail: slots 12..15; issue batch-1 prefetch (tokens 16..19) pre-barrier.
    DOTOK(x0, 12, lds_part[0]); LOADX(x0, 16)
    DOTOK(x1, 13, lds_part[0]); LOADX(x1, 17)
    DOTOK(x2, 14, lds_part[0]); LOADX(x2, 18)
    DOTOK(x3, 15, lds_part[0]); LOADX(x3, 19)

    __syncthreads();
    PHASEB(lds_part[0], base);

    // ---- Batch 1: tokens 16..31 (buffer 1; phase B read buffer 0) ----
    #pragma clang loop unroll(disable)
    for (int it = 0; it < 3; ++it) {
        const int t = it * 4;
        DOTOK(x0, t + 0, lds_part[1]); LOADX(x0, 16 + t + 4)
        DOTOK(x1, t + 1, lds_part[1]); LOADX(x1, 16 + t + 5)
        DOTOK(x2, t + 2, lds_part[1]); LOADX(x2, 16 + t + 6)
        DOTOK(x3, t + 3, lds_part[1]); LOADX(x3, 16 + t + 7)
    }
    DOTOK(x0, 12, lds_part[1]);
    DOTOK(x1, 13, lds_part[1]);
    DOTOK(x2, 14, lds_part[1]);
    DOTOK(x3, 15, lds_part[1]);

    __syncthreads();
    PHASEB(lds_part[1], base + 16);

    // Final cnt/ps reduction: fold lanes l, l^16, l^32, then cross-wave LDS.
    cnt_acc += __shfl_xor(cnt_acc, 16); cnt_acc += __shfl_xor(cnt_acc, 32);
    ps_acc  += __shfl_xor(ps_acc, 16);  ps_acc  += __shfl_xor(ps_acc, 32);
    if (lane < N_EXPERT) {
        lds_red[wave][0][lane] = cnt_acc;
        lds_red[wave][1][lane] = ps_acc;
    }
    __syncthreads();
    if (tid < 32) {
        const int el = tid & 15;
        const int which = tid >> 4;   // 0 = cnt, 1 = ps
        float v = lds_red[0][which][el] + lds_red[1][which][el]
                + lds_red[2][which][el] + lds_red[3][which][el];
        ws[blockIdx.x * 32 + tid] = v;
    }
#undef LOADX
#undef DOTOK
#undef PHASEB
}

__global__ __launch_bounds__(1024)
void loss_kernel(const float* __restrict__ ws, float* __restrict__ out)
{
    // Reduce NBLK x 32 partial slots with 1024 threads (coalesced 256B/wave),
    // then dot counts x prob-sums.
    __shared__ float red[32][33];   // +1 pad
    __shared__ float col[32];
    const int tid = threadIdx.x;    // 0..1023
    const int c   = tid & 31;       // column within slot
    const int r   = tid >> 5;       // 0..31 slot-chunk
    float s0 = 0.f, s1 = 0.f, s2 = 0.f, s3 = 0.f;
    #pragma unroll
    for (int k = 0; k < 32; k += 4) {
        s0 += ws[(size_t)(r + (k + 0) * 32) * 32 + c];
        s1 += ws[(size_t)(r + (k + 1) * 32) * 32 + c];
        s2 += ws[(size_t)(r + (k + 2) * 32) * 32 + c];
        s3 += ws[(size_t)(r + (k + 3) * 32) * 32 + c];
    }
    red[r][c] = (s0 + s1) + (s2 + s3);
    __syncthreads();
    if (tid < 32) {
        float t = 0.f;
        #pragma unroll
        for (int k = 0; k < 32; ++k) t += red[k][tid];
        col[tid] = t;
    }
    __syncthreads();
    if (tid == 0) {
        float sum = 0.f;
        #pragma unroll
        for (int e = 0; e < N_EXPERT; ++e)
            sum += col[e] * col[16 + e];
        out[4 * N_TOKENS] = sum * (float)N_EXPERT
                          / ((float)N_TOKENS * (float)N_TOKENS);
    }
}

extern "C" void kernel_launch(void* const* d_in, const int* in_sizes, int n_in,
                              void* d_out, int out_size, void* d_ws, size_t ws_size,
                              hipStream_t stream)
{
    const float* inp = (const float*)d_in[0];
    const float* W   = (const float*)d_in[1];
    float* out = (float*)d_out;
    float* ws  = (float*)d_ws;

    gate_kernel<<<NBLK, TPB, 0, stream>>>(inp, W, out, ws);
    loss_kernel<<<1, 1024, 0, stream>>>(ws, out);
}

// Round 14
// 38.852 us; speedup vs baseline: 7.6982x; 1.0091x over previous
//
#include <hip/hip_runtime.h>
#include <math.h>

#define N_TOKENS 32768
#define D_MODEL  1024
#define N_EXPERT 16
#define TPB      256
#define NBLK     1024              // 4 blocks/CU
#define TOKS     32                // tokens per block (2 batches of 16)
#define BATCH    16
#define EP       (N_EXPERT + 1)    // padded inner dim

typedef float f32x4 __attribute__((ext_vector_type(4)));
typedef float f32x2 __attribute__((ext_vector_type(2)));

// DPP cross-lane XOR within 16-lane rows (VALU pipe):
//   ^1: quad_perm [1,0,3,2]=0xB1; ^2: quad_perm [2,3,0,1]=0x4E;
//   ^8: row_ror:8 = 0x128 ((i+8) mod 16 == i^8).  (HW-verified rounds 6-12.)
// NOTE (r13 lesson): v_permlane16/32_swap_b32 folds FAILED correctness —
// semantic model wrong; masks 16/32 stay on __shfl_xor.
template<int CTRL>
static __device__ __forceinline__ float dpp_xor(float v) {
    return __int_as_float(__builtin_amdgcn_update_dpp(
        0, __float_as_int(v), CTRL, 0xF, 0xF, true));
}

// Packed fp32 dot over 4 dims: v_pk_mul + v_pk_fma + horizontal add.
// w passed BY VALUE only (r11 lesson: pointer into wreg[] -> scratch).
static __device__ __forceinline__ float dot4pk(f32x4 x, f32x4 w) {
    f32x2 xl = __builtin_shufflevector(x, x, 0, 1);
    f32x2 xh = __builtin_shufflevector(x, x, 2, 3);
    f32x2 wl = __builtin_shufflevector(w, w, 0, 1);
    f32x2 wh = __builtin_shufflevector(w, w, 2, 3);
    f32x2 m, r;
    asm("v_pk_mul_f32 %0, %1, %2" : "=v"(m) : "v"(xl), "v"(wl));
    asm("v_pk_fma_f32 %0, %1, %2, %3" : "=v"(r) : "v"(xh), "v"(wh), "v"(m));
    return r.x + r.y;
}

// d_out layout (float32, concatenated outputs):
//   [0, 65536)       top_k_indices as floats, row-major [N,2]
//   [65536, 131072)  top_k_scores,            row-major [N,2]
//   [131072]         loss scalar
// d_ws: NBLK slots of 32 floats; slot b: [0..15] expert counts, [16..31] prob sums.

__global__ __launch_bounds__(TPB)
__attribute__((amdgpu_waves_per_eu(4, 4)))
void gate_kernel(const float* __restrict__ inp,
                 const float* __restrict__ W,
                 float* __restrict__ out,
                 float* __restrict__ ws)
{
    const int tid  = threadIdx.x;
    const int wave = tid >> 6;
    const int lane = tid & 63;
    const int p    = lane & 15;               // expert rotation for this lane
    const int d0   = wave * 256 + lane * 4;   // this lane's 4 dims
    const int base = blockIdx.x * TOKS;

    // XOR-rotated W fragment: wreg[j] = W[j^p][d0..d0+3].  64 VGPRs.
    f32x4 wreg[N_EXPERT];
    #pragma unroll
    for (int j = 0; j < N_EXPERT; ++j)
        wreg[j] = *reinterpret_cast<const f32x4*>(W + (j ^ p) * D_MODEL + d0);

    __shared__ float lds_part[2][BATCH][4][EP];   // double-buffered, padded
    __shared__ float lds_red[4][2][N_EXPERT];     // final cnt/ps reduce

    float cnt_acc = 0.f;
    float ps_acc  = 0.f;

    const float* xptr = inp + (size_t)base * D_MODEL + d0;

#define LOADX(xr, t) xr = *reinterpret_cast<const f32x4*>(xptr + (size_t)(t) * D_MODEL);

    // Select-free transpose-reduce: masks 8,2,1 via DPP; masks 4,16,32 via
    // shfl (HW-verified).
#define DOTOK(xv, slot, BUF) do { \
    float a0 =dot4pk(xv,wreg[0]),  a1 =dot4pk(xv,wreg[1]);  \
    float a2 =dot4pk(xv,wreg[2]),  a3 =dot4pk(xv,wreg[3]);  \
    float a4 =dot4pk(xv,wreg[4]),  a5 =dot4pk(xv,wreg[5]);  \
    float a6 =dot4pk(xv,wreg[6]),  a7 =dot4pk(xv,wreg[7]);  \
    float a8 =dot4pk(xv,wreg[8]),  a9 =dot4pk(xv,wreg[9]);  \
    float a10=dot4pk(xv,wreg[10]), a11=dot4pk(xv,wreg[11]); \
    float a12=dot4pk(xv,wreg[12]), a13=dot4pk(xv,wreg[13]); \
    float a14=dot4pk(xv,wreg[14]), a15=dot4pk(xv,wreg[15]); \
    float b0 = a0 + dpp_xor<0x128>(a8);  \
    float b1 = a1 + dpp_xor<0x128>(a9);  \
    float b2 = a2 + dpp_xor<0x128>(a10); \
    float b3 = a3 + dpp_xor<0x128>(a11); \
    float b4 = a4 + dpp_xor<0x128>(a12); \
    float b5 = a5 + dpp_xor<0x128>(a13); \
    float b6 = a6 + dpp_xor<0x128>(a14); \
    float b7 = a7 + dpp_xor<0x128>(a15); \
    float c0 = b0 + __shfl_xor(b4, 4); \
    float c1 = b1 + __shfl_xor(b5, 4); \
    float c2 = b2 + __shfl_xor(b6, 4); \
    float c3 = b3 + __shfl_xor(b7, 4); \
    float d0_ = c0 + dpp_xor<0x4E>(c2); \
    float d1_ = c1 + dpp_xor<0x4E>(c3); \
    float s0  = d0_ + dpp_xor<0xB1>(d1_); \
    s0 += __shfl_xor(s0, 16); \
    s0 += __shfl_xor(s0, 32); \
    if (lane < N_EXPERT) BUF[slot][wave][lane] = s0; \
} while (0)

    // Phase B: 16 tokens x 16 expert-lanes: sum 4 wave partials, top-2
    // merge butterfly ((val desc, idx asc) == jax.lax.top_k), 2-way softmax.
#define PHASEB(BUF, TOKBASE) do { \
    const int tgrp = tid >> 4; \
    const int el   = tid & 15; \
    float v1 = BUF[tgrp][0][el] + BUF[tgrp][1][el] \
             + BUF[tgrp][2][el] + BUF[tgrp][3][el]; \
    int   i1 = el; \
    float v2 = -INFINITY; \
    int   i2 = 0; \
    _Pragma("unroll") \
    for (int m = 1; m <= 8; m <<= 1) { \
        float o1 = __shfl_xor(v1, m); \
        int  oi1 = __shfl_xor(i1, m); \
        float o2 = __shfl_xor(v2, m); \
        int  oi2 = __shfl_xor(i2, m); \
        bool afirst = (v1 > o1) || (v1 == o1 && i1 < oi1); \
        float c1v = afirst ? v1 : o1;   int c1i = afirst ? i1 : oi1; \
        float bv  = afirst ? o1 : v1;   int bi  = afirst ? oi1 : i1; \
        float sv  = afirst ? v2 : o2;   int si  = afirst ? i2 : oi2; \
        bool sgt  = (bv > sv) || (bv == sv && bi < si); \
        v1 = c1v; i1 = c1i; \
        v2 = sgt ? bv : sv;  i2 = sgt ? bi : si; \
    } \
    float tt = expf(v2 - v1); \
    float p1 = 1.f / (1.f + tt); \
    float p2 = tt * p1; \
    const int tok = (TOKBASE) + tgrp; \
    if (el == 0) { \
        *reinterpret_cast<float2*>(out + 2 * tok) = \
            make_float2((float)i1, (float)i2); \
        *reinterpret_cast<float2*>(out + 2 * N_TOKENS + 2 * tok) = \
            make_float2(p1, p2); \
    } \
    cnt_acc += (el == i1 ? 1.f : 0.f) + (el == i2 ? 1.f : 0.f); \
    ps_acc  += (el == i1 ? p1  : 0.f) + (el == i2 ? p2  : 0.f); \
} while (0)

    // 6-deep named prefetch ring: 6 tokens (~900 cy of work) in flight
    // covers the ~900 cy HBM miss latency (L3 evicted by harness ws-poison).
    f32x4 x0, x1, x2, x3, x4, x5;
    LOADX(x0, 0) LOADX(x1, 1) LOADX(x2, 2)
    LOADX(x3, 3) LOADX(x4, 4) LOADX(x5, 5)

    // ---- Batch 0: tokens 0..15 (ring loads run ahead to token 21) ----
    DOTOK(x0,  0, lds_part[0]); LOADX(x0,  6)
    DOTOK(x1,  1, lds_part[0]); LOADX(x1,  7)
    DOTOK(x2,  2, lds_part[0]); LOADX(x2,  8)
    DOTOK(x3,  3, lds_part[0]); LOADX(x3,  9)
    DOTOK(x4,  4, lds_part[0]); LOADX(x4, 10)
    DOTOK(x5,  5, lds_part[0]); LOADX(x5, 11)
    DOTOK(x0,  6, lds_part[0]); LOADX(x0, 12)
    DOTOK(x1,  7, lds_part[0]); LOADX(x1, 13)
    DOTOK(x2,  8, lds_part[0]); LOADX(x2, 14)
    DOTOK(x3,  9, lds_part[0]); LOADX(x3, 15)
    DOTOK(x4, 10, lds_part[0]); LOADX(x4, 16)
    DOTOK(x5, 11, lds_part[0]); LOADX(x5, 17)
    DOTOK(x0, 12, lds_part[0]); LOADX(x0, 18)
    DOTOK(x1, 13, lds_part[0]); LOADX(x1, 19)
    DOTOK(x2, 14, lds_part[0]); LOADX(x2, 20)
    DOTOK(x3, 15, lds_part[0]); LOADX(x3, 21)

    __syncthreads();
    PHASEB(lds_part[0], base);

    // ---- Batch 1: tokens 16..31; ring mapping continues (16->x4, 17->x5,
    // 18->x0, ...), writes buffer 1 (phase B read buffer 0). ----
    DOTOK(x4,  0, lds_part[1]); LOADX(x4, 22)
    DOTOK(x5,  1, lds_part[1]); LOADX(x5, 23)
    DOTOK(x0,  2, lds_part[1]); LOADX(x0, 24)
    DOTOK(x1,  3, lds_part[1]); LOADX(x1, 25)
    DOTOK(x2,  4, lds_part[1]); LOADX(x2, 26)
    DOTOK(x3,  5, lds_part[1]); LOADX(x3, 27)
    DOTOK(x4,  6, lds_part[1]); LOADX(x4, 28)
    DOTOK(x5,  7, lds_part[1]); LOADX(x5, 29)
    DOTOK(x0,  8, lds_part[1]); LOADX(x0, 30)
    DOTOK(x1,  9, lds_part[1]); LOADX(x1, 31)
    DOTOK(x2, 10, lds_part[1]);
    DOTOK(x3, 11, lds_part[1]);
    DOTOK(x4, 12, lds_part[1]);
    DOTOK(x5, 13, lds_part[1]);
    DOTOK(x0, 14, lds_part[1]);
    DOTOK(x1, 15, lds_part[1]);

    __syncthreads();
    PHASEB(lds_part[1], base + 16);

    // Final cnt/ps reduction: fold lanes l, l^16, l^32, then cross-wave LDS.
    cnt_acc += __shfl_xor(cnt_acc, 16); cnt_acc += __shfl_xor(cnt_acc, 32);
    ps_acc  += __shfl_xor(ps_acc, 16);  ps_acc  += __shfl_xor(ps_acc, 32);
    if (lane < N_EXPERT) {
        lds_red[wave][0][lane] = cnt_acc;
        lds_red[wave][1][lane] = ps_acc;
    }
    __syncthreads();
    if (tid < 32) {
        const int el = tid & 15;
        const int which = tid >> 4;   // 0 = cnt, 1 = ps
        float v = lds_red[0][which][el] + lds_red[1][which][el]
                + lds_red[2][which][el] + lds_red[3][which][el];
        ws[blockIdx.x * 32 + tid] = v;
    }
#undef LOADX
#undef DOTOK
#undef PHASEB
}

__global__ __launch_bounds__(1024)
void loss_kernel(const float* __restrict__ ws, float* __restrict__ out)
{
    // Reduce NBLK x 32 partial slots with 1024 threads (coalesced 256B/wave),
    // then dot counts x prob-sums.
    __shared__ float red[32][33];   // +1 pad
    __shared__ float col[32];
    const int tid = threadIdx.x;    // 0..1023
    const int c   = tid & 31;       // column within slot
    const int r   = tid >> 5;       // 0..31 slot-chunk
    float s0 = 0.f, s1 = 0.f, s2 = 0.f, s3 = 0.f;
    #pragma unroll
    for (int k = 0; k < 32; k += 4) {
        s0 += ws[(size_t)(r + (k + 0) * 32) * 32 + c];
        s1 += ws[(size_t)(r + (k + 1) * 32) * 32 + c];
        s2 += ws[(size_t)(r + (k + 2) * 32) * 32 + c];
        s3 += ws[(size_t)(r + (k + 3) * 32) * 32 + c];
    }
    red[r][c] = (s0 + s1) + (s2 + s3);
    __syncthreads();
    if (tid < 32) {
        float t = 0.f;
        #pragma unroll
        for (int k = 0; k < 32; ++k) t += red[k][tid];
        col[tid] = t;
    }
    __syncthreads();
    if (tid == 0) {
        float sum = 0.f;
        #pragma unroll
        for (int e = 0; e < N_EXPERT; ++e)
            sum += col[e] * col[16 + e];
        out[4 * N_TOKENS] = sum * (float)N_EXPERT
                          / ((float)N_TOKENS * (float)N_TOKENS);
    }
}

extern "C" void kernel_launch(void* const* d_in, const int* in_sizes, int n_in,
                              void* d_out, int out_size, void* d_ws, size_t ws_size,
                              hipStream_t stream)
{
    const float* inp = (const float*)d_in[0];
    const float* W   = (const float*)d_in[1];
    float* out = (float*)d_out;
    float* ws  = (float*)d_ws;

    gate_kernel<<<NBLK, TPB, 0, stream>>>(inp, W, out, ws);
    loss_kernel<<<1, 1024, 0, stream>>>(ws, out);
}